// Round 3
// baseline (118.355 us; speedup 1.0000x reference)
//
#include <hip/hip_runtime.h>

// Elementwise: out[i] = x[i] > 0 ? x[i]*x[i] : x[i]
// N = 2^26 fp32. Memory-bound: 512 MiB total traffic.
// R1: 107.7us = 4.99 TB/s (62% peak). Fix: unroll x4 (4 loads in flight
// before stores) + nontemporal hints for streaming data.
// R2 fix: nontemporal builtins require native clang vector type, not
// HIP_vector_type<float,4> — use ext_vector_type(4).

typedef float f4 __attribute__((ext_vector_type(4)));

__global__ __launch_bounds__(256) void sq_pos_kernel(const f4* __restrict__ x,
                                                     f4* __restrict__ out,
                                                     long long nvec) {
    const long long stride = (long long)gridDim.x * blockDim.x;
    long long i = (long long)blockIdx.x * blockDim.x + threadIdx.x;

    auto f = [](f4 v) -> f4 {
        f4 r;
        r.x = v.x > 0.0f ? v.x * v.x : v.x;
        r.y = v.y > 0.0f ? v.y * v.y : v.y;
        r.z = v.z > 0.0f ? v.z * v.z : v.z;
        r.w = v.w > 0.0f ? v.w * v.w : v.w;
        return r;
    };

    // Main loop: 4 independent loads issued before any store (MLP).
    for (; i + 3 * stride < nvec; i += 4 * stride) {
        f4 v0 = __builtin_nontemporal_load(&x[i]);
        f4 v1 = __builtin_nontemporal_load(&x[i + stride]);
        f4 v2 = __builtin_nontemporal_load(&x[i + 2 * stride]);
        f4 v3 = __builtin_nontemporal_load(&x[i + 3 * stride]);
        __builtin_nontemporal_store(f(v0), &out[i]);
        __builtin_nontemporal_store(f(v1), &out[i + stride]);
        __builtin_nontemporal_store(f(v2), &out[i + 2 * stride]);
        __builtin_nontemporal_store(f(v3), &out[i + 3 * stride]);
    }
    // Tail (not hit for N=2^26 with this grid, but safe).
    for (; i < nvec; i += stride) {
        f4 v = __builtin_nontemporal_load(&x[i]);
        __builtin_nontemporal_store(f(v), &out[i]);
    }
}

__global__ void sq_pos_tail(const float* __restrict__ x, float* __restrict__ o,
                            long long start, long long n) {
    long long i = start + threadIdx.x;
    if (i < n) { float v = x[i]; o[i] = v > 0.0f ? v * v : v; }
}

extern "C" void kernel_launch(void* const* d_in, const int* in_sizes, int n_in,
                              void* d_out, int out_size, void* d_ws, size_t ws_size,
                              hipStream_t stream) {
    const f4* x = (const f4*)d_in[0];
    f4* out = (f4*)d_out;
    long long n = in_sizes[0];
    long long nvec = n / 4;  // N = 2^26, divisible by 4

    const int block = 256;
    long long want = (nvec + block - 1) / block;
    int grid = (int)(want < 2048 ? want : 2048);

    sq_pos_kernel<<<grid, block, 0, stream>>>(x, out, nvec);

    long long tail_start = nvec * 4;
    if (tail_start < n) {
        sq_pos_tail<<<1, 64, 0, stream>>>((const float*)d_in[0], (float*)d_out,
                                          tail_start, n);
    }
}

// Round 4
// 96.617 us; speedup vs baseline: 1.2250x; 1.2250x over previous
//
#include <hip/hip_runtime.h>

// Elementwise: out[i] = x[i] > 0 ? x[i]*x[i] : x[i]
// N = 2^26 fp32. Memory-bound: 512 MiB total traffic. Ceiling ~85us @ 6.3 TB/s.
// R1: grid-stride float4, 107.7us = 4.99 TB/s.
// R3: unroll x4 (8MiB-apart streams) + nt hints = 118us REGRESSION.
// R4: unbundle — block-contiguous unroll x4 (16KiB tile/block), no nt,
//     no loop: exactly one tile per block, 4 loads in flight per wave.

typedef float f4 __attribute__((ext_vector_type(4)));

__global__ __launch_bounds__(256) void sq_pos_kernel(const f4* __restrict__ x,
                                                     f4* __restrict__ out) {
    // Block tile: 4*256 f4 = 16 KiB. Thread t covers tile + t + k*256.
    const long long base = (long long)blockIdx.x * (4 * 256) + threadIdx.x;

    f4 v0 = x[base];
    f4 v1 = x[base + 256];
    f4 v2 = x[base + 512];
    f4 v3 = x[base + 768];

    auto f = [](f4 v) -> f4 {
        f4 r;
        r.x = v.x > 0.0f ? v.x * v.x : v.x;
        r.y = v.y > 0.0f ? v.y * v.y : v.y;
        r.z = v.z > 0.0f ? v.z * v.z : v.z;
        r.w = v.w > 0.0f ? v.w * v.w : v.w;
        return r;
    };

    out[base]       = f(v0);
    out[base + 256] = f(v1);
    out[base + 512] = f(v2);
    out[base + 768] = f(v3);
}

// Generic fallback for sizes not divisible by 4096 floats (not hit for N=2^26).
__global__ void sq_pos_tail(const float* __restrict__ x, float* __restrict__ o,
                            long long start, long long n) {
    long long i = start + (long long)blockIdx.x * blockDim.x + threadIdx.x;
    if (i < n) { float v = x[i]; o[i] = v > 0.0f ? v * v : v; }
}

extern "C" void kernel_launch(void* const* d_in, const int* in_sizes, int n_in,
                              void* d_out, int out_size, void* d_ws, size_t ws_size,
                              hipStream_t stream) {
    const float* xf = (const float*)d_in[0];
    float* of = (float*)d_out;
    long long n = in_sizes[0];

    // Main kernel: each block handles 1024 f4 = 4096 floats.
    long long nblocks = n / 4096;
    if (nblocks > 0) {
        sq_pos_kernel<<<(int)nblocks, 256, 0, stream>>>((const f4*)xf, (f4*)of);
    }
    long long done = nblocks * 4096;
    if (done < n) {
        long long rem = n - done;
        int tgrid = (int)((rem + 255) / 256);
        sq_pos_tail<<<tgrid, 256, 0, stream>>>(xf, of, done, n);
    }
}